// Round 2
// baseline (895.907 us; speedup 1.0000x reference)
//
#include <hip/hip_runtime.h>
#include <hip/hip_bf16.h>
#include <math.h>

// Problem constants (match reference)
#define B 128
#define S 1024
#define H 768
#define NH 8
#define DH 96
#define FUSED 2312
#define SCALE 0.10206207261596575f  // 1/sqrt(96)

// ---------------------------------------------------------------------------
// K1: asp_query[b,:] = mean of last_hidden rows in (sep1, sep2), or row 0.
// ---------------------------------------------------------------------------
__global__ void aspq_kernel(const float* __restrict__ lh,
                            const int* __restrict__ sep1,
                            const int* __restrict__ sep2,
                            float* __restrict__ aspq) {
    int b = blockIdx.x;
    int s1 = sep1[b], s2 = sep2[b];
    int lo, hi;
    if (s2 > s1 + 1) { lo = s1 + 1; hi = s2; } else { lo = 0; hi = 1; }
    int t = threadIdx.x;
    const float* base = lh + ((size_t)b * S + lo) * H;
    float a0 = 0.f, a1 = 0.f, a2 = 0.f;
    int n = hi - lo;
    for (int s = 0; s < n; ++s) {
        const float* r = base + (size_t)s * H;
        a0 += r[t];
        a1 += r[t + 256];
        a2 += r[t + 512];
    }
    float inv = 1.0f / (float)n;
    aspq[b * H + t]       = a0 * inv;
    aspq[b * H + t + 256] = a1 * inv;
    aspq[b * H + t + 512] = a2 * inv;
}

// ---------------------------------------------------------------------------
// Generic small fp32 GEMM:  C[M,N] = act(A[M,K] @ op(W) + bias)
//  WT=false: W is [N,K] row-major (W^T product, PyTorch Linear style)
//  WT=true : W is [K,N] row-major (plain A@W)
//  HEADSEL : A column base shifts by (n0/96)*768 (head-select for ctx GEMM)
//  z-batched via blockIdx.z with per-operand strides.
// ---------------------------------------------------------------------------
template <int ACT, bool WT, bool HEADSEL>
__global__ void gemm_kernel(const float* __restrict__ A, int lda, int a_bs,
                            const float* __restrict__ W, int ldw, int w_bs,
                            const float* __restrict__ bias,
                            float* __restrict__ C, int ldc, int c_bs,
                            int M, int N, int K) {
    A += (size_t)blockIdx.z * a_bs;
    W += (size_t)blockIdx.z * w_bs;
    C += (size_t)blockIdx.z * c_bs;
    int n0 = blockIdx.x * 32, m0 = blockIdx.y * 32;
    if (HEADSEL) A += (n0 / DH) * H;
    __shared__ float As[32][33];
    __shared__ float Ws[32][33];
    int t = threadIdx.x;
    int tx = t & 31, ty = t >> 5;  // ty in 0..7
    float acc[4] = {0.f, 0.f, 0.f, 0.f};
    for (int k0 = 0; k0 < K; k0 += 32) {
#pragma unroll
        for (int i = 0; i < 4; ++i) {
            int e = t + 256 * i;
            int r = e >> 5, cl = e & 31;
            int m = m0 + r, k = k0 + cl;
            As[r][cl] = (m < M && k < K) ? A[(size_t)m * lda + k] : 0.f;
        }
#pragma unroll
        for (int i = 0; i < 4; ++i) {
            int e = t + 256 * i;
            int r = e >> 5, cl = e & 31;
            if (!WT) {
                int n = n0 + r, k = k0 + cl;
                Ws[r][cl] = (n < N && k < K) ? W[(size_t)n * ldw + k] : 0.f;
            } else {
                int k = k0 + r, n = n0 + cl;
                Ws[cl][r] = (n < N && k < K) ? W[(size_t)k * ldw + n] : 0.f;
            }
        }
        __syncthreads();
#pragma unroll
        for (int kk = 0; kk < 32; ++kk) {
            float wv = Ws[tx][kk];
#pragma unroll
            for (int i = 0; i < 4; ++i)
                acc[i] += As[ty + 8 * i][kk] * wv;
        }
        __syncthreads();
    }
    int n = n0 + tx;
    if (n < N) {
        float bb = bias ? bias[n] : 0.f;
#pragma unroll
        for (int i = 0; i < 4; ++i) {
            int m = m0 + ty + 8 * i;
            if (m < M) {
                float x = acc[i] + bb;
                if (ACT == 1) x = 0.5f * x * (1.0f + erff(x * 0.70710678118654752f));
                C[(size_t)m * ldc + n] = x;
            }
        }
    }
}

// ---------------------------------------------------------------------------
// K3: scores[b,h,s] = SCALE * lh[b,s,:] . U[b,h,:]   for s in text span
// grid: (S/64, B), 256 threads (4 waves x 16 rows each)
// ---------------------------------------------------------------------------
__global__ void scores_kernel(const float* __restrict__ lh,
                              const float* __restrict__ U,
                              const int* __restrict__ sep1,
                              float* __restrict__ scores) {
    int b = blockIdx.y;
    int s1 = sep1[b];
    int tlo = (s1 > 1) ? 1 : 0;
    int thi = (s1 > 1) ? s1 : 1;
    int r0 = blockIdx.x * 64;
    if (r0 >= thi) return;
    __shared__ float Us[NH][H];
    const float* Ub = U + (size_t)b * NH * H;
    for (int i = threadIdx.x; i < NH * H; i += 256)
        ((float*)Us)[i] = Ub[i];
    __syncthreads();
    int wave = threadIdx.x >> 6, lane = threadIdx.x & 63;
    for (int i = 0; i < 16; ++i) {
        int s = r0 + wave * 16 + i;
        if (s < tlo || s >= thi) continue;
        const float* row = lh + ((size_t)b * S + s) * H;
        float acc[NH];
#pragma unroll
        for (int h = 0; h < NH; ++h) acc[h] = 0.f;
#pragma unroll
        for (int jj = 0; jj < H / 64; ++jj) {
            float x = row[lane + jj * 64];
#pragma unroll
            for (int h = 0; h < NH; ++h) acc[h] += x * Us[h][lane + jj * 64];
        }
#pragma unroll
        for (int h = 0; h < NH; ++h) {
            float v = acc[h];
            for (int off = 32; off; off >>= 1) v += __shfl_xor(v, off);
            if (lane == h)
                scores[((size_t)(b * NH + h)) * S + s] = v * SCALE;
        }
    }
}

// ---------------------------------------------------------------------------
// K4: in-place softmax over the text span, per (b,h). grid: B, 256 threads
// ---------------------------------------------------------------------------
__global__ void softmax_kernel(float* __restrict__ sc,
                               const int* __restrict__ sep1) {
    int b = blockIdx.x;
    int s1 = sep1[b];
    int tlo = (s1 > 1) ? 1 : 0;
    int thi = (s1 > 1) ? s1 : 1;
    int span = thi - tlo;
    __shared__ float red[4];
    int wave = threadIdx.x >> 6, lane = threadIdx.x & 63;
    for (int h = 0; h < NH; ++h) {
        float* row = sc + ((size_t)(b * NH + h)) * S + tlo;
        float m = -1e30f;
        for (int i = threadIdx.x; i < span; i += 256) m = fmaxf(m, row[i]);
        for (int off = 32; off; off >>= 1) m = fmaxf(m, __shfl_xor(m, off));
        if (lane == 0) red[wave] = m;
        __syncthreads();
        m = fmaxf(fmaxf(red[0], red[1]), fmaxf(red[2], red[3]));
        __syncthreads();
        float sum = 0.f;
        for (int i = threadIdx.x; i < span; i += 256) {
            float e = __expf(row[i] - m);
            row[i] = e;
            sum += e;
        }
        for (int off = 32; off; off >>= 1) sum += __shfl_xor(sum, off);
        if (lane == 0) red[wave] = sum;
        __syncthreads();
        float tot = red[0] + red[1] + red[2] + red[3];
        float inv = 1.0f / tot;
        for (int i = threadIdx.x; i < span; i += 256) row[i] *= inv;
        __syncthreads();
    }
}

// ---------------------------------------------------------------------------
// K5: wsum[b,h,c] = sum_s attn[b,h,s] * lh[b,s,c]  over text span
// grid: (3, B), 256 threads (each thread owns one column)
// ---------------------------------------------------------------------------
__global__ void wsum_kernel(const float* __restrict__ lh,
                            const float* __restrict__ attn,
                            const int* __restrict__ sep1,
                            float* __restrict__ wsum) {
    int b = blockIdx.y;
    int c = blockIdx.x * 256 + threadIdx.x;
    int s1 = sep1[b];
    int tlo = (s1 > 1) ? 1 : 0;
    int thi = (s1 > 1) ? s1 : 1;
    int span = thi - tlo;
    __shared__ float at[NH * 800];
    for (int i = threadIdx.x; i < NH * span; i += 256) {
        int h = i / span, s = i - h * span;
        at[h * span + s] = attn[((size_t)(b * NH + h)) * S + tlo + s];
    }
    __syncthreads();
    float acc[NH];
#pragma unroll
    for (int h = 0; h < NH; ++h) acc[h] = 0.f;
    const float* base = lh + ((size_t)b * S + tlo) * H + c;
    for (int s = 0; s < span; ++s) {
        float x = base[(size_t)s * H];
#pragma unroll
        for (int h = 0; h < NH; ++h) acc[h] += at[h * span + s] * x;
    }
#pragma unroll
    for (int h = 0; h < NH; ++h)
        wsum[((size_t)(b * NH + h)) * H + c] = acc[h];
}

// ---------------------------------------------------------------------------
// K9: assemble fused[b, 2312] = [lh[b,0,:], cross, asp_query, <LN slot>]
// ---------------------------------------------------------------------------
__global__ void fuse_kernel(const float* __restrict__ lh,
                            const float* __restrict__ cross,
                            const float* __restrict__ aspq,
                            float* __restrict__ fused) {
    int b = blockIdx.x, t = threadIdx.x;
    float* fb = fused + (size_t)b * FUSED;
    const float* lhb = lh + (size_t)b * S * H;
    for (int i = t; i < H; i += 256) {
        fb[i]         = lhb[i];
        fb[H + i]     = cross[b * H + i];
        fb[2 * H + i] = aspq[b * H + i];
    }
}

__global__ void fuse_ln_kernel(const float* __restrict__ aro_f,
                               const float* __restrict__ ln_g,
                               const float* __restrict__ ln_b,
                               float* __restrict__ fused) {
    int b = blockIdx.x, t = threadIdx.x;  // t < 8
    const float* af = aro_f + b * 8;
    float mu = 0.f;
#pragma unroll
    for (int j = 0; j < 8; ++j) mu += af[j];
    mu *= 0.125f;
    float var = 0.f;
#pragma unroll
    for (int j = 0; j < 8; ++j) { float d = af[j] - mu; var += d * d; }
    var *= 0.125f;
    float x = (af[t] - mu) * rsqrtf(var + 1e-5f) * ln_g[t] + ln_b[t];
    fused[(size_t)b * FUSED + 3 * H + t] = x;
}

// ---------------------------------------------------------------------------
// K12: heads — va = hdn2 @ va_w3.T + b3 ; pol/aro = fused @ w.T + b
// grid: B, 256 threads (4 waves x 2 outputs)
// out layout: [va(128x2) | pol(128x3) | aro(128x3)]
// ---------------------------------------------------------------------------
__global__ void heads_kernel(const float* __restrict__ fused,
                             const float* __restrict__ hdn2,
                             const float* __restrict__ va_w3,
                             const float* __restrict__ va_b3,
                             const float* __restrict__ pol_w,
                             const float* __restrict__ pol_b,
                             const float* __restrict__ aro_w,
                             const float* __restrict__ aro_b,
                             float* __restrict__ out) {
    int b = blockIdx.x;
    int wave = threadIdx.x >> 6, lane = threadIdx.x & 63;
    __shared__ float fs[FUSED];
    __shared__ float hs[128];
    for (int i = threadIdx.x; i < FUSED; i += 256) fs[i] = fused[(size_t)b * FUSED + i];
    for (int i = threadIdx.x; i < 128; i += 256) hs[i] = hdn2[b * 128 + i];
    __syncthreads();
    for (int oi = 0; oi < 2; ++oi) {
        int o = wave * 2 + oi;  // 0..7
        const float* w;
        const float* src;
        int K;
        float bia;
        float* dst;
        if (o < 2)      { w = va_w3 + o * 128;         src = hs; K = 128;   bia = va_b3[o];     dst = out + b * 2 + o; }
        else if (o < 5) { int r = o - 2; w = pol_w + r * FUSED; src = fs; K = FUSED; bia = pol_b[r]; dst = out + 256 + b * 3 + r; }
        else            { int r = o - 5; w = aro_w + r * FUSED; src = fs; K = FUSED; bia = aro_b[r]; dst = out + 640 + b * 3 + r; }
        float acc = 0.f;
        for (int i = lane; i < K; i += 64) acc += src[i] * w[i];
        for (int off = 32; off; off >>= 1) acc += __shfl_xor(acc, off);
        if (lane == 0) *dst = acc + bia;
    }
}

// ---------------------------------------------------------------------------
extern "C" void kernel_launch(void* const* d_in, const int* in_sizes, int n_in,
                              void* d_out, int out_size, void* d_ws, size_t ws_size,
                              hipStream_t stream) {
    const float* lh    = (const float*)d_in[0];
    const float* aro_f = (const float*)d_in[1];
    const int*   sep1  = (const int*)d_in[2];
    const int*   sep2  = (const int*)d_in[3];
    const float* in_w  = (const float*)d_in[4];
    const float* in_b  = (const float*)d_in[5];
    const float* out_w = (const float*)d_in[6];
    const float* out_b = (const float*)d_in[7];
    const float* ln_g  = (const float*)d_in[8];
    const float* ln_b  = (const float*)d_in[9];
    const float* va_w1 = (const float*)d_in[10];
    const float* va_b1 = (const float*)d_in[11];
    const float* va_w2 = (const float*)d_in[12];
    const float* va_b2 = (const float*)d_in[13];
    const float* va_w3 = (const float*)d_in[14];
    const float* va_b3 = (const float*)d_in[15];
    const float* pol_w = (const float*)d_in[16];
    const float* pol_b = (const float*)d_in[17];
    const float* aro_w = (const float*)d_in[18];
    const float* aro_b = (const float*)d_in[19];
    float* out = (float*)d_out;

    float* ws = (float*)d_ws;
    float* aspq   = ws;                     // B*H
    float* qbuf   = aspq + B * H;           // B*H
    float* Ubuf   = qbuf + B * H;           // B*NH*H
    float* scores = Ubuf + B * NH * H;      // B*NH*S (attn in place)
    float* wsum   = scores + B * NH * S;    // B*NH*H
    float* ctx    = wsum + B * NH * H;      // B*H
    float* cross  = ctx + B * H;            // B*H
    float* fusedb = cross + B * H;          // B*FUSED
    float* hdn1   = fusedb + B * FUSED;     // B*512
    float* hdn2   = hdn1 + B * 512;         // B*128

    const float* wq = in_w;                  // rows [0,768)
    const float* wk = in_w + H * H;          // rows [768,1536)
    const float* wv = in_w + 2 * H * H;      // rows [1536,2304)
    const float* bq = in_b;
    const float* bv = in_b + 2 * H;

    // 1) asp_query
    aspq_kernel<<<B, 256, 0, stream>>>(lh, sep1, sep2, aspq);
    // 2) q = aspq @ wq.T + bq     [128,768]
    gemm_kernel<0, false, false><<<dim3(24, 4, 1), 256, 0, stream>>>(
        aspq, H, 0, wq, H, 0, bq, qbuf, H, 0, B, H, H);
    // 3) U[b,h,:] = q_h @ wk_h    (z = head)
    gemm_kernel<0, true, false><<<dim3(24, 4, NH), 256, 0, stream>>>(
        qbuf, H, DH, wk, H, DH * H, nullptr, Ubuf, NH * H, H, B, H, DH);
    // 4) scores (masked, scaled)
    scores_kernel<<<dim3(S / 64, B), 256, 0, stream>>>(lh, Ubuf, sep1, scores);
    // 5) softmax in place
    softmax_kernel<<<B, 256, 0, stream>>>(scores, sep1);
    // 6) weighted V row-sum
    wsum_kernel<<<dim3(3, B), 256, 0, stream>>>(lh, scores, sep1, wsum);
    // 7) ctx = wv_h @ wsum + bv   (head-block-diagonal A)
    gemm_kernel<0, false, true><<<dim3(24, 4, 1), 256, 0, stream>>>(
        wsum, NH * H, 0, wv, H, 0, bv, ctx, H, 0, B, H, H);
    // 8) cross = ctx @ out_w.T + out_b
    gemm_kernel<0, false, false><<<dim3(24, 4, 1), 256, 0, stream>>>(
        ctx, H, 0, out_w, H, 0, out_b, cross, H, 0, B, H, H);
    // 9) fused assembly + LN
    fuse_kernel<<<B, 256, 0, stream>>>(lh, cross, aspq, fusedb);
    fuse_ln_kernel<<<B, 8, 0, stream>>>(aro_f, ln_g, ln_b, fusedb);
    // 10) hdn1 = gelu(fused @ va_w1.T + b1)   [128,512] K=2312
    gemm_kernel<1, false, false><<<dim3(16, 4, 1), 256, 0, stream>>>(
        fusedb, FUSED, 0, va_w1, FUSED, 0, va_b1, hdn1, 512, 0, B, 512, FUSED);
    // 11) hdn2 = gelu(hdn1 @ va_w2.T + b2)    [128,128] K=512
    gemm_kernel<1, false, false><<<dim3(4, 4, 1), 256, 0, stream>>>(
        hdn1, 512, 0, va_w2, 512, 0, va_b2, hdn2, 128, 0, B, 128, 512);
    // 12) heads -> out
    heads_kernel<<<B, 256, 0, stream>>>(fusedb, hdn2, va_w3, va_b3,
                                        pol_w, pol_b, aro_w, aro_b, out);
}

// Round 3
// 470.444 us; speedup vs baseline: 1.9044x; 1.9044x over previous
//
#include <hip/hip_runtime.h>
#include <hip/hip_bf16.h>
#include <math.h>

#define B 128
#define S 1024
#define H 768
#define NH 8
#define DH 96
#define FUSED 2312
#define FPAD 2432            // fused row stride, padded to 19*128
#define KSPLIT 19
#define KCHUNK 128
#define SCALE 0.10206207261596575f  // 1/sqrt(96)
#define GELU_C 0.70710678118654752f

__device__ __forceinline__ float dot4(float4 a, float4 b) {
    return a.x * b.x + a.y * b.y + a.z * b.z + a.w * b.w;
}

// ---------------------------------------------------------------------------
// K1: asp_query[b,:] = mean of last_hidden rows in (sep1, sep2), or row 0.
// 192 threads, float4 per thread, 2-row unroll.
// ---------------------------------------------------------------------------
__global__ void aspq_kernel(const float* __restrict__ lh,
                            const int* __restrict__ sep1,
                            const int* __restrict__ sep2,
                            float* __restrict__ aspq) {
    int b = blockIdx.x;
    int s1 = sep1[b], s2 = sep2[b];
    int lo, hi;
    if (s2 > s1 + 1) { lo = s1 + 1; hi = s2; } else { lo = 0; hi = 1; }
    int t = threadIdx.x;                 // 0..191
    const float* base = lh + ((size_t)b * S + lo) * H + 4 * t;
    float4 a0 = {0.f, 0.f, 0.f, 0.f}, a1 = {0.f, 0.f, 0.f, 0.f};
    int n = hi - lo;
    int s = 0;
    for (; s + 1 < n; s += 2) {
        float4 r0 = *(const float4*)(base + (size_t)s * H);
        float4 r1 = *(const float4*)(base + (size_t)(s + 1) * H);
        a0.x += r0.x; a0.y += r0.y; a0.z += r0.z; a0.w += r0.w;
        a1.x += r1.x; a1.y += r1.y; a1.z += r1.z; a1.w += r1.w;
    }
    if (s < n) {
        float4 r0 = *(const float4*)(base + (size_t)s * H);
        a0.x += r0.x; a0.y += r0.y; a0.z += r0.z; a0.w += r0.w;
    }
    float inv = 1.0f / (float)n;
    float4 o;
    o.x = (a0.x + a1.x) * inv;
    o.y = (a0.y + a1.y) * inv;
    o.z = (a0.z + a1.z) * inv;
    o.w = (a0.w + a1.w) * inv;
    *(float4*)(aspq + b * H + 4 * t) = o;
}

// ---------------------------------------------------------------------------
// Generic small fp32 GEMM, float4 global loads, 32x32 tiles.
//  TAG distinguishes instantiations in rocprof.
//  WT=false: W is [N,K] row-major; WT=true: W is [K,N] row-major.
//  HEADSEL: A base shifts by (n0/96)*768 (head-block-diag A for ctx GEMM).
//  KCL: clamp W k-address (for split-K tail vs zero-padded A).
// Requires: M,N,K multiples handled by caller (M=128; N%32==0; K%32==0).
// ---------------------------------------------------------------------------
template <int TAG, int ACT, bool WT, bool HEADSEL, bool KCL>
__global__ void gemm_kernel(const float* __restrict__ A, int lda, int a_bs,
                            const float* __restrict__ W, int ldw, int w_bs,
                            const float* __restrict__ bias,
                            float* __restrict__ C, int ldc, int c_bs,
                            int M, int N, int K, int kclamp) {
    A += (size_t)blockIdx.z * a_bs;
    W += (size_t)blockIdx.z * w_bs;
    C += (size_t)blockIdx.z * c_bs;
    int kcl = KCL ? (kclamp - (int)blockIdx.z * w_bs) : 0;
    int n0 = blockIdx.x * 32, m0 = blockIdx.y * 32;
    if (HEADSEL) A += (n0 / DH) * H;
    __shared__ float As[32][33];
    __shared__ float Ws[32][33];
    int t = threadIdx.x;
    int tx = t & 31, ty = t >> 5;         // compute mapping
    int lr = t >> 3, lc = (t & 7) * 4;    // load mapping (row, col4)
    float acc[4] = {0.f, 0.f, 0.f, 0.f};
    for (int k0 = 0; k0 < K; k0 += 32) {
        {
            float4 a = *(const float4*)(A + (size_t)(m0 + lr) * lda + k0 + lc);
            As[lr][lc] = a.x; As[lr][lc + 1] = a.y;
            As[lr][lc + 2] = a.z; As[lr][lc + 3] = a.w;
        }
        if (!WT) {
            int kk = k0 + lc;
            if (KCL) kk = min(kk, kcl);
            float4 w = *(const float4*)(W + (size_t)(n0 + lr) * ldw + kk);
            Ws[lr][lc] = w.x; Ws[lr][lc + 1] = w.y;
            Ws[lr][lc + 2] = w.z; Ws[lr][lc + 3] = w.w;
        } else {
            float4 w = *(const float4*)(W + (size_t)(k0 + lr) * ldw + n0 + lc);
            Ws[lc][lr] = w.x; Ws[lc + 1][lr] = w.y;
            Ws[lc + 2][lr] = w.z; Ws[lc + 3][lr] = w.w;
        }
        __syncthreads();
#pragma unroll
        for (int kk = 0; kk < 32; ++kk) {
            float wv = Ws[tx][kk];
#pragma unroll
            for (int i = 0; i < 4; ++i)
                acc[i] += As[ty + 8 * i][kk] * wv;
        }
        __syncthreads();
    }
    int n = n0 + tx;
    if (n < N) {
        float bb = bias ? bias[n] : 0.f;
#pragma unroll
        for (int i = 0; i < 4; ++i) {
            int m = m0 + ty + 8 * i;
            if (m < M) {
                float x = acc[i] + bb;
                if (ACT == 1) x = 0.5f * x * (1.0f + erff(x * GELU_C));
                C[(size_t)m * ldc + n] = x;
            }
        }
    }
}

// ---------------------------------------------------------------------------
// K3: scores[b,h,s] = SCALE * lh[b,s,:] . U[b,h,:]  for s in text span
// grid (16, B), 256 threads. float4 loads, U staged as float4 in LDS.
// ---------------------------------------------------------------------------
__global__ void scores_kernel(const float* __restrict__ lh,
                              const float* __restrict__ U,
                              const int* __restrict__ sep1,
                              float* __restrict__ scores) {
    int b = blockIdx.y;
    int s1 = sep1[b];
    int tlo = (s1 > 1) ? 1 : 0;
    int thi = (s1 > 1) ? s1 : 1;
    int r0 = blockIdx.x * 64;
    if (r0 >= thi) return;
    __shared__ float4 Us[NH * 192];
    const float4* Ub = (const float4*)(U + (size_t)b * NH * H);
    for (int i = threadIdx.x; i < NH * 192; i += 256) Us[i] = Ub[i];
    __syncthreads();
    int wave = threadIdx.x >> 6, lane = threadIdx.x & 63;
    for (int i = 0; i < 16; ++i) {
        int s = r0 + wave * 16 + i;
        if (s < tlo || s >= thi) continue;
        const float4* row = (const float4*)(lh + ((size_t)b * S + s) * H);
        float4 x0 = row[lane], x1 = row[lane + 64], x2 = row[lane + 128];
        float acc[NH];
#pragma unroll
        for (int h = 0; h < NH; ++h) {
            acc[h] = dot4(x0, Us[h * 192 + lane])
                   + dot4(x1, Us[h * 192 + lane + 64])
                   + dot4(x2, Us[h * 192 + lane + 128]);
        }
#pragma unroll
        for (int h = 0; h < NH; ++h) {
            float v = acc[h];
            for (int off = 32; off; off >>= 1) v += __shfl_xor(v, off);
            if (lane == h)
                scores[((size_t)(b * NH + h)) * S + s] = v * SCALE;
        }
    }
}

// ---------------------------------------------------------------------------
// K4: in-place softmax over the text span, per b. grid B, 256 threads.
// ---------------------------------------------------------------------------
__global__ void softmax_kernel(float* __restrict__ sc,
                               const int* __restrict__ sep1) {
    int b = blockIdx.x;
    int s1 = sep1[b];
    int tlo = (s1 > 1) ? 1 : 0;
    int thi = (s1 > 1) ? s1 : 1;
    int span = thi - tlo;
    __shared__ float red[4];
    int wave = threadIdx.x >> 6, lane = threadIdx.x & 63;
    for (int h = 0; h < NH; ++h) {
        float* row = sc + ((size_t)(b * NH + h)) * S + tlo;
        float m = -1e30f;
        for (int i = threadIdx.x; i < span; i += 256) m = fmaxf(m, row[i]);
        for (int off = 32; off; off >>= 1) m = fmaxf(m, __shfl_xor(m, off));
        if (lane == 0) red[wave] = m;
        __syncthreads();
        m = fmaxf(fmaxf(red[0], red[1]), fmaxf(red[2], red[3]));
        __syncthreads();
        float sum = 0.f;
        for (int i = threadIdx.x; i < span; i += 256) {
            float e = __expf(row[i] - m);
            row[i] = e;
            sum += e;
        }
        for (int off = 32; off; off >>= 1) sum += __shfl_xor(sum, off);
        if (lane == 0) red[wave] = sum;
        __syncthreads();
        float tot = red[0] + red[1] + red[2] + red[3];
        float inv = 1.0f / tot;
        for (int i = threadIdx.x; i < span; i += 256) row[i] *= inv;
        __syncthreads();
    }
}

// ---------------------------------------------------------------------------
// K5: wsum partials. grid (B, 2), 192 threads; thread owns 4 cols (float4).
// z-th block takes rows tlo+z, tlo+z+2, ...
// ---------------------------------------------------------------------------
__global__ void wsum_kernel(const float* __restrict__ lh,
                            const float* __restrict__ attn,
                            const int* __restrict__ sep1,
                            float* __restrict__ wsp) {
    int b = blockIdx.x, z = blockIdx.y, t = threadIdx.x;
    int s1 = sep1[b];
    int tlo = (s1 > 1) ? 1 : 0;
    int thi = (s1 > 1) ? s1 : 1;
    float4 acc[NH];
#pragma unroll
    for (int h = 0; h < NH; ++h) acc[h] = {0.f, 0.f, 0.f, 0.f};
    const float* base = lh + ((size_t)b * S) * H + 4 * t;
    for (int s = tlo + z; s < thi; s += 2) {
        float4 x = *(const float4*)(base + (size_t)s * H);
#pragma unroll
        for (int h = 0; h < NH; ++h) {
            float p = attn[((size_t)(b * NH + h)) * S + s];
            acc[h].x += p * x.x; acc[h].y += p * x.y;
            acc[h].z += p * x.z; acc[h].w += p * x.w;
        }
    }
    float* o = wsp + (size_t)z * (B * NH * H) + (size_t)b * NH * H + 4 * t;
#pragma unroll
    for (int h = 0; h < NH; ++h) *(float4*)(o + h * H) = acc[h];
}

__global__ void wsum_merge_kernel(const float* __restrict__ wsp,
                                  float* __restrict__ wsum) {
    size_t i = ((size_t)blockIdx.x * 256 + threadIdx.x) * 4;
    float4 a = *(const float4*)(wsp + i);
    float4 c = *(const float4*)(wsp + (size_t)B * NH * H + i);
    float4 o = {a.x + c.x, a.y + c.y, a.z + c.z, a.w + c.w};
    *(float4*)(wsum + i) = o;
}

// ---------------------------------------------------------------------------
// K9: fused[b, 0:2312] = [lh[b,0,:], cross, asp_query, <LN written later>],
// pad [2312, FPAD) with zeros (stride FPAD).
// ---------------------------------------------------------------------------
__global__ void fuse_kernel(const float* __restrict__ lh,
                            const float* __restrict__ cross,
                            const float* __restrict__ aspq,
                            float* __restrict__ fused) {
    int b = blockIdx.x, t = threadIdx.x;
    float* fb = fused + (size_t)b * FPAD;
    const float* lhb = lh + (size_t)b * S * H;
    for (int i = t; i < H; i += 256) {
        fb[i]         = lhb[i];
        fb[H + i]     = cross[b * H + i];
        fb[2 * H + i] = aspq[b * H + i];
    }
    for (int i = t; i < FPAD - FUSED; i += 256) fb[FUSED + i] = 0.f;
}

__global__ void fuse_ln_kernel(const float* __restrict__ aro_f,
                               const float* __restrict__ ln_g,
                               const float* __restrict__ ln_b,
                               float* __restrict__ fused) {
    int b = blockIdx.x, t = threadIdx.x;  // t < 8
    const float* af = aro_f + b * 8;
    float mu = 0.f;
#pragma unroll
    for (int j = 0; j < 8; ++j) mu += af[j];
    mu *= 0.125f;
    float var = 0.f;
#pragma unroll
    for (int j = 0; j < 8; ++j) { float d = af[j] - mu; var += d * d; }
    var *= 0.125f;
    float x = (af[t] - mu) * rsqrtf(var + 1e-5f) * ln_g[t] + ln_b[t];
    fused[(size_t)b * FPAD + 3 * H + t] = x;
}

// ---------------------------------------------------------------------------
// K13: mlp2 — reduce hdn1 split-K partials + bias + gelu -> hs[512];
// hdn2 = gelu(hs @ va_w2.T + b2) -> h2[128]; then all 8 head outputs.
// grid B, 256 threads.
// ---------------------------------------------------------------------------
__global__ void mlp2_kernel(const float* __restrict__ hdn1p,
                            const float* __restrict__ fusedb,
                            const float* __restrict__ va_b1,
                            const float* __restrict__ va_w2,
                            const float* __restrict__ va_b2,
                            const float* __restrict__ va_w3,
                            const float* __restrict__ va_b3,
                            const float* __restrict__ pol_w,
                            const float* __restrict__ pol_b,
                            const float* __restrict__ aro_w,
                            const float* __restrict__ aro_b,
                            float* __restrict__ out) {
    int b = blockIdx.x, t = threadIdx.x;
    __shared__ float hs[512];
    __shared__ float h2[128];
    for (int n = t; n < 512; n += 256) {
        float sacc = 0.f;
#pragma unroll
        for (int z = 0; z < KSPLIT; ++z)
            sacc += hdn1p[(size_t)z * (B * 512) + b * 512 + n];
        sacc += va_b1[n];
        hs[n] = 0.5f * sacc * (1.0f + erff(sacc * GELU_C));
    }
    __syncthreads();
    int wave = t >> 6, lane = t & 63;
    for (int i = 0; i < 32; ++i) {
        int n = wave * 32 + i;  // 0..127
        float a = 0.f;
#pragma unroll
        for (int j = 0; j < 8; ++j) {
            int k = lane + 64 * j;
            a += hs[k] * va_w2[(size_t)n * 512 + k];
        }
        for (int off = 32; off; off >>= 1) a += __shfl_xor(a, off);
        if (lane == 0) {
            float x = a + va_b2[n];
            h2[n] = 0.5f * x * (1.0f + erff(x * GELU_C));
        }
    }
    __syncthreads();
    const float* fb = fusedb + (size_t)b * FPAD;
    for (int oi = 0; oi < 2; ++oi) {
        int o = wave * 2 + oi;  // 0..7
        float acc = 0.f, bia;
        float* dst;
        if (o < 2) {
            for (int k = lane; k < 128; k += 64) acc += h2[k] * va_w3[o * 128 + k];
            bia = va_b3[o]; dst = out + b * 2 + o;
        } else if (o < 5) {
            int r = o - 2;
            for (int k = lane; k < FUSED; k += 64) acc += fb[k] * pol_w[(size_t)r * FUSED + k];
            bia = pol_b[r]; dst = out + 256 + b * 3 + r;
        } else {
            int r = o - 5;
            for (int k = lane; k < FUSED; k += 64) acc += fb[k] * aro_w[(size_t)r * FUSED + k];
            bia = aro_b[r]; dst = out + 640 + b * 3 + r;
        }
        for (int off = 32; off; off >>= 1) acc += __shfl_xor(acc, off);
        if (lane == 0) *dst = acc + bia;
    }
}

// ---------------------------------------------------------------------------
extern "C" void kernel_launch(void* const* d_in, const int* in_sizes, int n_in,
                              void* d_out, int out_size, void* d_ws, size_t ws_size,
                              hipStream_t stream) {
    const float* lh    = (const float*)d_in[0];
    const float* aro_f = (const float*)d_in[1];
    const int*   sep1  = (const int*)d_in[2];
    const int*   sep2  = (const int*)d_in[3];
    const float* in_w  = (const float*)d_in[4];
    const float* in_b  = (const float*)d_in[5];
    const float* out_w = (const float*)d_in[6];
    const float* out_b = (const float*)d_in[7];
    const float* ln_g  = (const float*)d_in[8];
    const float* ln_b  = (const float*)d_in[9];
    const float* va_w1 = (const float*)d_in[10];
    const float* va_b1 = (const float*)d_in[11];
    const float* va_w2 = (const float*)d_in[12];
    const float* va_b2 = (const float*)d_in[13];
    const float* va_w3 = (const float*)d_in[14];
    const float* va_b3 = (const float*)d_in[15];
    const float* pol_w = (const float*)d_in[16];
    const float* pol_b = (const float*)d_in[17];
    const float* aro_w = (const float*)d_in[18];
    const float* aro_b = (const float*)d_in[19];
    float* out = (float*)d_out;

    float* ws = (float*)d_ws;
    float* aspq   = ws;                         // 98304
    float* qbuf   = aspq + B * H;               // 98304
    float* Ubuf   = qbuf + B * H;               // 786432
    float* scores = Ubuf + B * NH * H;          // 1048576 (attn in place)
    float* wsp    = scores + B * NH * S;        // 1572864 (2 partials)
    float* wsum   = wsp + 2 * B * NH * H;       // 786432
    float* ctx    = wsum + B * NH * H;          // 98304
    float* cross  = ctx + B * H;                // 98304
    float* fusedb = cross + B * H;              // 311296 (stride FPAD)
    float* hdn1p  = Ubuf;                       // overlay: 19*65536=1245184 <= Ubuf+scores (dead by then)

    const float* wq = in_w;
    const float* wk = in_w + H * H;
    const float* wv = in_w + 2 * H * H;
    const float* bq = in_b;
    const float* bv = in_b + 2 * H;

    // 1) asp_query
    aspq_kernel<<<B, 192, 0, stream>>>(lh, sep1, sep2, aspq);
    // 2) q = aspq @ wq.T + bq
    gemm_kernel<0, 0, false, false, false><<<dim3(24, 4, 1), 256, 0, stream>>>(
        aspq, H, 0, wq, H, 0, bq, qbuf, H, 0, B, H, H, 0);
    // 3) U[b,h,:] = q_h @ wk_h   (z = head, WT)
    gemm_kernel<1, 0, true, false, false><<<dim3(24, 4, NH), 256, 0, stream>>>(
        qbuf, H, DH, wk, H, DH * H, nullptr, Ubuf, NH * H, H, B, H, DH, 0);
    // 4) scores (masked, scaled)
    scores_kernel<<<dim3(16, B), 256, 0, stream>>>(lh, Ubuf, sep1, scores);
    // 5) softmax in place
    softmax_kernel<<<B, 256, 0, stream>>>(scores, sep1);
    // 6) weighted V row-sum partials + merge
    wsum_kernel<<<dim3(B, 2), 192, 0, stream>>>(lh, scores, sep1, wsp);
    wsum_merge_kernel<<<(B * NH * H) / 1024, 256, 0, stream>>>(wsp, wsum);
    // 7) ctx = wv_h @ wsum_h + bv
    gemm_kernel<2, 0, false, true, false><<<dim3(24, 4, 1), 256, 0, stream>>>(
        wsum, NH * H, 0, wv, H, 0, bv, ctx, H, 0, B, H, H, 0);
    // 8) cross = ctx @ out_w.T + out_b
    gemm_kernel<3, 0, false, false, false><<<dim3(24, 4, 1), 256, 0, stream>>>(
        ctx, H, 0, out_w, H, 0, out_b, cross, H, 0, B, H, H, 0);
    // 9) fused assembly (padded) + LN slot
    fuse_kernel<<<B, 256, 0, stream>>>(lh, cross, aspq, fusedb);
    fuse_ln_kernel<<<B, 8, 0, stream>>>(aro_f, ln_g, ln_b, fusedb);
    // 10) hdn1 split-K partials: z=0..18, K-chunk 128 (A zero-padded, W clamped)
    gemm_kernel<4, 0, false, false, true><<<dim3(16, 4, KSPLIT), 256, 0, stream>>>(
        fusedb, FPAD, KCHUNK, va_w1, FUSED, KCHUNK, nullptr,
        hdn1p, 512, B * 512, B, 512, KCHUNK, FUSED - 4);
    // 11) mlp2: reduce+gelu + hdn2 + all heads
    mlp2_kernel<<<B, 256, 0, stream>>>(hdn1p, fusedb, va_b1, va_w2, va_b2,
                                       va_w3, va_b3, pol_w, pol_b,
                                       aro_w, aro_b, out);
}

// Round 4
// 438.966 us; speedup vs baseline: 2.0409x; 1.0717x over previous
//
#include <hip/hip_runtime.h>
#include <hip/hip_bf16.h>
#include <math.h>

#define B 128
#define S 1024
#define H 768
#define NH 8
#define DH 96
#define FUSED 2312
#define FPAD 2432            // fused row stride, padded to 19*128
#define KSPLIT 19
#define KCHUNK 128
#define SCALE 0.10206207261596575f  // 1/sqrt(96)
#define GELU_C 0.70710678118654752f

__device__ __forceinline__ float dot4(float4 a, float4 b) {
    return a.x * b.x + a.y * b.y + a.z * b.z + a.w * b.w;
}

// ---------------------------------------------------------------------------
// K1a: asp_query partials. grid (B, 4), 192 threads (float4 cols).
// Slice z takes rows lo+z, lo+z+4, ...
// ---------------------------------------------------------------------------
__global__ void aspq_part_kernel(const float* __restrict__ lh,
                                 const int* __restrict__ sep1,
                                 const int* __restrict__ sep2,
                                 float* __restrict__ aspp) {
    int b = blockIdx.x, z = blockIdx.y, t = threadIdx.x;
    int s1 = sep1[b], s2 = sep2[b];
    int lo, hi;
    if (s2 > s1 + 1) { lo = s1 + 1; hi = s2; } else { lo = 0; hi = 1; }
    const float* base = lh + ((size_t)b * S) * H + 4 * t;
    float4 a = {0.f, 0.f, 0.f, 0.f};
    for (int s = lo + z; s < hi; s += 4) {
        float4 r = *(const float4*)(base + (size_t)s * H);
        a.x += r.x; a.y += r.y; a.z += r.z; a.w += r.w;
    }
    *(float4*)(aspp + (size_t)z * (B * H) + b * H + 4 * t) = a;
}

// K1b: merge 4 partials, divide by n. grid B, 192 threads.
__global__ void aspq_merge_kernel(const float* __restrict__ aspp,
                                  const int* __restrict__ sep1,
                                  const int* __restrict__ sep2,
                                  float* __restrict__ aspq) {
    int b = blockIdx.x, t = threadIdx.x;
    int s1 = sep1[b], s2 = sep2[b];
    int lo, hi;
    if (s2 > s1 + 1) { lo = s1 + 1; hi = s2; } else { lo = 0; hi = 1; }
    float inv = 1.0f / (float)(hi - lo);
    float4 a = {0.f, 0.f, 0.f, 0.f};
#pragma unroll
    for (int z = 0; z < 4; ++z) {
        float4 r = *(const float4*)(aspp + (size_t)z * (B * H) + b * H + 4 * t);
        a.x += r.x; a.y += r.y; a.z += r.z; a.w += r.w;
    }
    float4 o = {a.x * inv, a.y * inv, a.z * inv, a.w * inv};
    *(float4*)(aspq + b * H + 4 * t) = o;
}

// ---------------------------------------------------------------------------
// Generic small fp32 GEMM, float4 global loads, 32x32 tiles.
// ---------------------------------------------------------------------------
template <int TAG, int ACT, bool WT, bool HEADSEL, bool KCL>
__global__ void gemm_kernel(const float* __restrict__ A, int lda, int a_bs,
                            const float* __restrict__ W, int ldw, int w_bs,
                            const float* __restrict__ bias,
                            float* __restrict__ C, int ldc, int c_bs,
                            int M, int N, int K, int kclamp) {
    A += (size_t)blockIdx.z * a_bs;
    W += (size_t)blockIdx.z * w_bs;
    C += (size_t)blockIdx.z * c_bs;
    int kcl = KCL ? (kclamp - (int)blockIdx.z * w_bs) : 0;
    int n0 = blockIdx.x * 32, m0 = blockIdx.y * 32;
    if (HEADSEL) A += (n0 / DH) * H;
    __shared__ float As[32][33];
    __shared__ float Ws[32][33];
    int t = threadIdx.x;
    int tx = t & 31, ty = t >> 5;
    int lr = t >> 3, lc = (t & 7) * 4;
    float acc[4] = {0.f, 0.f, 0.f, 0.f};
    for (int k0 = 0; k0 < K; k0 += 32) {
        {
            float4 a = *(const float4*)(A + (size_t)(m0 + lr) * lda + k0 + lc);
            As[lr][lc] = a.x; As[lr][lc + 1] = a.y;
            As[lr][lc + 2] = a.z; As[lr][lc + 3] = a.w;
        }
        if (!WT) {
            int kk = k0 + lc;
            if (KCL) kk = min(kk, kcl);
            float4 w = *(const float4*)(W + (size_t)(n0 + lr) * ldw + kk);
            Ws[lr][lc] = w.x; Ws[lr][lc + 1] = w.y;
            Ws[lr][lc + 2] = w.z; Ws[lr][lc + 3] = w.w;
        } else {
            float4 w = *(const float4*)(W + (size_t)(k0 + lr) * ldw + n0 + lc);
            Ws[lc][lr] = w.x; Ws[lc + 1][lr] = w.y;
            Ws[lc + 2][lr] = w.z; Ws[lc + 3][lr] = w.w;
        }
        __syncthreads();
#pragma unroll
        for (int kk = 0; kk < 32; ++kk) {
            float wv = Ws[tx][kk];
#pragma unroll
            for (int i = 0; i < 4; ++i)
                acc[i] += As[ty + 8 * i][kk] * wv;
        }
        __syncthreads();
    }
    int n = n0 + tx;
    if (n < N) {
        float bb = bias ? bias[n] : 0.f;
#pragma unroll
        for (int i = 0; i < 4; ++i) {
            int m = m0 + ty + 8 * i;
            if (m < M) {
                float x = acc[i] + bb;
                if (ACT == 1) x = 0.5f * x * (1.0f + erff(x * GELU_C));
                C[(size_t)m * ldc + n] = x;
            }
        }
    }
}

// ---------------------------------------------------------------------------
// K3: scores[b,h,s] = SCALE * lh[b,s,:] . U[b,h,:]  for s in text span
// grid (16, B), 256 threads.
// ---------------------------------------------------------------------------
__global__ void scores_kernel(const float* __restrict__ lh,
                              const float* __restrict__ U,
                              const int* __restrict__ sep1,
                              float* __restrict__ scores) {
    int b = blockIdx.y;
    int s1 = sep1[b];
    int tlo = (s1 > 1) ? 1 : 0;
    int thi = (s1 > 1) ? s1 : 1;
    int r0 = blockIdx.x * 64;
    if (r0 >= thi) return;
    __shared__ float4 Us[NH * 192];
    const float4* Ub = (const float4*)(U + (size_t)b * NH * H);
    for (int i = threadIdx.x; i < NH * 192; i += 256) Us[i] = Ub[i];
    __syncthreads();
    int wave = threadIdx.x >> 6, lane = threadIdx.x & 63;
    for (int i = 0; i < 16; ++i) {
        int s = r0 + wave * 16 + i;
        if (s < tlo || s >= thi) continue;
        const float4* row = (const float4*)(lh + ((size_t)b * S + s) * H);
        float4 x0 = row[lane], x1 = row[lane + 64], x2 = row[lane + 128];
        float acc[NH];
#pragma unroll
        for (int h = 0; h < NH; ++h) {
            acc[h] = dot4(x0, Us[h * 192 + lane])
                   + dot4(x1, Us[h * 192 + lane + 64])
                   + dot4(x2, Us[h * 192 + lane + 128]);
        }
#pragma unroll
        for (int h = 0; h < NH; ++h) {
            float v = acc[h];
            for (int off = 32; off; off >>= 1) v += __shfl_xor(v, off);
            if (lane == h)
                scores[((size_t)(b * NH + h)) * S + s] = v * SCALE;
        }
    }
}

// ---------------------------------------------------------------------------
// K4: softmax over text span; writes transposed attn_t[b][s][h].
// grid B, 256 threads; wave w handles heads w and w+4, all in registers.
// span <= 799 <= 13*64.
// ---------------------------------------------------------------------------
__global__ void softmax_kernel(const float* __restrict__ sc,
                               const int* __restrict__ sep1,
                               float* __restrict__ attn_t) {
    int b = blockIdx.x;
    int wave = threadIdx.x >> 6, lane = threadIdx.x & 63;
    int s1 = sep1[b];
    int tlo = (s1 > 1) ? 1 : 0;
    int thi = (s1 > 1) ? s1 : 1;
    int span = thi - tlo;
#pragma unroll
    for (int hh = 0; hh < 2; ++hh) {
        int h = wave + 4 * hh;
        const float* row = sc + ((size_t)(b * NH + h)) * S + tlo;
        float buf[13];
#pragma unroll
        for (int j = 0; j < 13; ++j) {
            int i = lane + 64 * j;
            buf[j] = (i < span) ? row[i] : -1e30f;
        }
        float m = buf[0];
#pragma unroll
        for (int j = 1; j < 13; ++j) m = fmaxf(m, buf[j]);
        for (int off = 32; off; off >>= 1) m = fmaxf(m, __shfl_xor(m, off));
        float sum = 0.f;
#pragma unroll
        for (int j = 0; j < 13; ++j) {
            float e = __expf(buf[j] - m);
            buf[j] = e;
            sum += e;
        }
        for (int off = 32; off; off >>= 1) sum += __shfl_xor(sum, off);
        float inv = 1.0f / sum;
#pragma unroll
        for (int j = 0; j < 13; ++j) {
            int i = lane + 64 * j;
            if (i < span)
                attn_t[((size_t)b * S + tlo + i) * NH + h] = buf[j] * inv;
        }
    }
}

// ---------------------------------------------------------------------------
// K5: wsum partials. grid (B, 2), 768 threads; thread owns one column.
// attn_t gives 8 probs as 2 broadcast float4 loads.
// ---------------------------------------------------------------------------
__global__ void wsum_kernel(const float* __restrict__ lh,
                            const float* __restrict__ attn_t,
                            const int* __restrict__ sep1,
                            float* __restrict__ wsp) {
    int b = blockIdx.x, z = blockIdx.y, t = threadIdx.x;
    int s1 = sep1[b];
    int tlo = (s1 > 1) ? 1 : 0;
    int thi = (s1 > 1) ? s1 : 1;
    float acc[NH];
#pragma unroll
    for (int h = 0; h < NH; ++h) acc[h] = 0.f;
    const float* base = lh + ((size_t)b * S) * H + t;
    const float4* ab = (const float4*)(attn_t + ((size_t)b * S) * NH);
    for (int s = tlo + z; s < thi; s += 2) {
        float x = base[(size_t)s * H];
        float4 p0 = ab[2 * s];
        float4 p1 = ab[2 * s + 1];
        acc[0] += p0.x * x; acc[1] += p0.y * x;
        acc[2] += p0.z * x; acc[3] += p0.w * x;
        acc[4] += p1.x * x; acc[5] += p1.y * x;
        acc[6] += p1.z * x; acc[7] += p1.w * x;
    }
    float* o = wsp + (size_t)z * (B * NH * H) + (size_t)b * NH * H + t;
#pragma unroll
    for (int h = 0; h < NH; ++h) o[h * H] = acc[h];
}

__global__ void wsum_merge_kernel(const float* __restrict__ wsp,
                                  float* __restrict__ wsum) {
    size_t i = ((size_t)blockIdx.x * 256 + threadIdx.x) * 4;
    float4 a = *(const float4*)(wsp + i);
    float4 c = *(const float4*)(wsp + (size_t)B * NH * H + i);
    float4 o = {a.x + c.x, a.y + c.y, a.z + c.z, a.w + c.w};
    *(float4*)(wsum + i) = o;
}

// ---------------------------------------------------------------------------
// K9: fused[b, 0:2312] = [lh[b,0,:], cross, asp_query, LN(arousal)],
// zero-pad [2312, FPAD).
// ---------------------------------------------------------------------------
__global__ void fuse_kernel(const float* __restrict__ lh,
                            const float* __restrict__ cross,
                            const float* __restrict__ aspq,
                            const float* __restrict__ aro_f,
                            const float* __restrict__ ln_g,
                            const float* __restrict__ ln_b,
                            float* __restrict__ fused) {
    int b = blockIdx.x, t = threadIdx.x;
    float* fb = fused + (size_t)b * FPAD;
    const float* lhb = lh + (size_t)b * S * H;
    for (int i = t; i < H; i += 256) {
        fb[i]         = lhb[i];
        fb[H + i]     = cross[b * H + i];
        fb[2 * H + i] = aspq[b * H + i];
    }
    for (int i = t; i < FPAD - FUSED; i += 256) fb[FUSED + i] = 0.f;
    if (t < 8) {
        const float* af = aro_f + b * 8;
        float mu = 0.f;
#pragma unroll
        for (int j = 0; j < 8; ++j) mu += af[j];
        mu *= 0.125f;
        float var = 0.f;
#pragma unroll
        for (int j = 0; j < 8; ++j) { float d = af[j] - mu; var += d * d; }
        var *= 0.125f;
        fb[3 * H + t] = (af[t] - mu) * rsqrtf(var + 1e-5f) * ln_g[t] + ln_b[t];
    }
}

// ---------------------------------------------------------------------------
// K13: mlp2 — reduce hdn1 split-K partials + bias + gelu -> hs[512];
// hdn2 = gelu(hs @ va_w2.T + b2) -> h2[128]; then all 8 head outputs.
// ---------------------------------------------------------------------------
__global__ void mlp2_kernel(const float* __restrict__ hdn1p,
                            const float* __restrict__ fusedb,
                            const float* __restrict__ va_b1,
                            const float* __restrict__ va_w2,
                            const float* __restrict__ va_b2,
                            const float* __restrict__ va_w3,
                            const float* __restrict__ va_b3,
                            const float* __restrict__ pol_w,
                            const float* __restrict__ pol_b,
                            const float* __restrict__ aro_w,
                            const float* __restrict__ aro_b,
                            float* __restrict__ out) {
    int b = blockIdx.x, t = threadIdx.x;
    __shared__ float hs[512];
    __shared__ float h2[128];
    for (int n = t; n < 512; n += 256) {
        float sacc = 0.f;
#pragma unroll
        for (int z = 0; z < KSPLIT; ++z)
            sacc += hdn1p[(size_t)z * (B * 512) + b * 512 + n];
        sacc += va_b1[n];
        hs[n] = 0.5f * sacc * (1.0f + erff(sacc * GELU_C));
    }
    __syncthreads();
    int wave = t >> 6, lane = t & 63;
    for (int i = 0; i < 32; ++i) {
        int n = wave * 32 + i;
        float a = 0.f;
#pragma unroll
        for (int j = 0; j < 8; ++j) {
            int k = lane + 64 * j;
            a += hs[k] * va_w2[(size_t)n * 512 + k];
        }
        for (int off = 32; off; off >>= 1) a += __shfl_xor(a, off);
        if (lane == 0) {
            float x = a + va_b2[n];
            h2[n] = 0.5f * x * (1.0f + erff(x * GELU_C));
        }
    }
    __syncthreads();
    const float* fb = fusedb + (size_t)b * FPAD;
    for (int oi = 0; oi < 2; ++oi) {
        int o = wave * 2 + oi;
        float acc = 0.f, bia;
        float* dst;
        if (o < 2) {
            for (int k = lane; k < 128; k += 64) acc += h2[k] * va_w3[o * 128 + k];
            bia = va_b3[o]; dst = out + b * 2 + o;
        } else if (o < 5) {
            int r = o - 2;
            for (int k = lane; k < FUSED; k += 64) acc += fb[k] * pol_w[(size_t)r * FUSED + k];
            bia = pol_b[r]; dst = out + 256 + b * 3 + r;
        } else {
            int r = o - 5;
            for (int k = lane; k < FUSED; k += 64) acc += fb[k] * aro_w[(size_t)r * FUSED + k];
            bia = aro_b[r]; dst = out + 640 + b * 3 + r;
        }
        for (int off = 32; off; off >>= 1) acc += __shfl_xor(acc, off);
        if (lane == 0) *dst = acc + bia;
    }
}

// ---------------------------------------------------------------------------
extern "C" void kernel_launch(void* const* d_in, const int* in_sizes, int n_in,
                              void* d_out, int out_size, void* d_ws, size_t ws_size,
                              hipStream_t stream) {
    const float* lh    = (const float*)d_in[0];
    const float* aro_f = (const float*)d_in[1];
    const int*   sep1  = (const int*)d_in[2];
    const int*   sep2  = (const int*)d_in[3];
    const float* in_w  = (const float*)d_in[4];
    const float* in_b  = (const float*)d_in[5];
    const float* out_w = (const float*)d_in[6];
    const float* out_b = (const float*)d_in[7];
    const float* ln_g  = (const float*)d_in[8];
    const float* ln_b  = (const float*)d_in[9];
    const float* va_w1 = (const float*)d_in[10];
    const float* va_b1 = (const float*)d_in[11];
    const float* va_w2 = (const float*)d_in[12];
    const float* va_b2 = (const float*)d_in[13];
    const float* va_w3 = (const float*)d_in[14];
    const float* va_b3 = (const float*)d_in[15];
    const float* pol_w = (const float*)d_in[16];
    const float* pol_b = (const float*)d_in[17];
    const float* aro_w = (const float*)d_in[18];
    const float* aro_b = (const float*)d_in[19];
    float* out = (float*)d_out;

    float* ws = (float*)d_ws;
    // layout (floats):
    float* aspp   = ws;                           //  393216 (4 slices)
    float* aspq   = aspp + 4 * B * H;             //   98304
    float* qbuf   = aspq + B * H;                 //   98304
    float* Ubuf   = qbuf + B * H;                 //  786432
    float* scores = Ubuf + B * NH * H;            // 1048576
    float* attn_t = scores + B * NH * S;          // 1048576
    float* wsp    = attn_t + B * S * NH;          // 1572864 (2 slices)
    float* wsum   = wsp + 2 * B * NH * H;         //  786432
    float* ctx    = wsum + B * NH * H;            //   98304
    float* cross  = ctx + B * H;                  //   98304
    float* fusedb = cross + B * H;                //  311296 (stride FPAD)
    float* hdn1p  = scores;                       // overlay: 1245184 <= scores+attn_t (dead)

    const float* wq = in_w;
    const float* wk = in_w + H * H;
    const float* wv = in_w + 2 * H * H;
    const float* bq = in_b;
    const float* bv = in_b + 2 * H;

    // 1) asp_query (partials + merge)
    aspq_part_kernel<<<dim3(B, 4), 192, 0, stream>>>(lh, sep1, sep2, aspp);
    aspq_merge_kernel<<<B, 192, 0, stream>>>(aspp, sep1, sep2, aspq);
    // 2) q = aspq @ wq.T + bq
    gemm_kernel<0, 0, false, false, false><<<dim3(24, 4, 1), 256, 0, stream>>>(
        aspq, H, 0, wq, H, 0, bq, qbuf, H, 0, B, H, H, 0);
    // 3) U[b,h,:] = q_h @ wk_h
    gemm_kernel<1, 0, true, false, false><<<dim3(24, 4, NH), 256, 0, stream>>>(
        qbuf, H, DH, wk, H, DH * H, nullptr, Ubuf, NH * H, H, B, H, DH, 0);
    // 4) scores
    scores_kernel<<<dim3(16, B), 256, 0, stream>>>(lh, Ubuf, sep1, scores);
    // 5) softmax -> attn_t (transposed)
    softmax_kernel<<<B, 256, 0, stream>>>(scores, sep1, attn_t);
    // 6) weighted V row-sum partials + merge
    wsum_kernel<<<dim3(B, 2), 768, 0, stream>>>(lh, attn_t, sep1, wsp);
    wsum_merge_kernel<<<(B * NH * H) / 1024, 256, 0, stream>>>(wsp, wsum);
    // 7) ctx = wv_h @ wsum_h + bv
    gemm_kernel<2, 0, false, true, false><<<dim3(24, 4, 1), 256, 0, stream>>>(
        wsum, NH * H, 0, wv, H, 0, bv, ctx, H, 0, B, H, H, 0);
    // 8) cross = ctx @ out_w.T + out_b
    gemm_kernel<3, 0, false, false, false><<<dim3(24, 4, 1), 256, 0, stream>>>(
        ctx, H, 0, out_w, H, 0, out_b, cross, H, 0, B, H, H, 0);
    // 9) fused assembly (+LN, +pad)
    fuse_kernel<<<B, 256, 0, stream>>>(lh, cross, aspq, aro_f, ln_g, ln_b, fusedb);
    // 10) hdn1 split-K partials
    gemm_kernel<4, 0, false, false, true><<<dim3(16, 4, KSPLIT), 256, 0, stream>>>(
        fusedb, FPAD, KCHUNK, va_w1, FUSED, KCHUNK, nullptr,
        hdn1p, 512, B * 512, B, 512, KCHUNK, FUSED - 4);
    // 11) mlp2: reduce+gelu + hdn2 + heads
    mlp2_kernel<<<B, 256, 0, stream>>>(hdn1p, fusedb, va_b1, va_w2, va_b2,
                                       va_w3, va_b3, pol_w, pol_b,
                                       aro_w, aro_b, out);
}

// Round 5
// 280.189 us; speedup vs baseline: 3.1975x; 1.5667x over previous
//
#include <hip/hip_runtime.h>
#include <hip/hip_bf16.h>
#include <math.h>

#define B 128
#define S 1024
#define H 768
#define NH 8
#define DH 96
#define FUSED 2312
#define FPAD 2432            // fused row stride, padded to 19*128
#define KSPLIT 19
#define KCHUNK 128
#define NSL 4                // flash slices per sample
#define CH 12                // rows per flash chunk (one per wave)
#define SCALE 0.10206207261596575f  // 1/sqrt(96)
#define GELU_C 0.70710678118654752f

__device__ __forceinline__ float dot4(float4 a, float4 b) {
    return a.x * b.x + a.y * b.y + a.z * b.z + a.w * b.w;
}

// ---------------------------------------------------------------------------
// K1a: asp_query partials. grid (B, 4), 192 threads (float4 cols).
// ---------------------------------------------------------------------------
__global__ void aspq_part_kernel(const float* __restrict__ lh,
                                 const int* __restrict__ sep1,
                                 const int* __restrict__ sep2,
                                 float* __restrict__ aspp) {
    int b = blockIdx.x, z = blockIdx.y, t = threadIdx.x;
    int s1 = sep1[b], s2 = sep2[b];
    int lo, hi;
    if (s2 > s1 + 1) { lo = s1 + 1; hi = s2; } else { lo = 0; hi = 1; }
    const float* base = lh + ((size_t)b * S) * H + 4 * t;
    float4 a = {0.f, 0.f, 0.f, 0.f};
    for (int s = lo + z; s < hi; s += 4) {
        float4 r = *(const float4*)(base + (size_t)s * H);
        a.x += r.x; a.y += r.y; a.z += r.z; a.w += r.w;
    }
    *(float4*)(aspp + (size_t)z * (B * H) + b * H + 4 * t) = a;
}

__global__ void aspq_merge_kernel(const float* __restrict__ aspp,
                                  const int* __restrict__ sep1,
                                  const int* __restrict__ sep2,
                                  float* __restrict__ aspq) {
    int b = blockIdx.x, t = threadIdx.x;
    int s1 = sep1[b], s2 = sep2[b];
    int lo, hi;
    if (s2 > s1 + 1) { lo = s1 + 1; hi = s2; } else { lo = 0; hi = 1; }
    float inv = 1.0f / (float)(hi - lo);
    float4 a = {0.f, 0.f, 0.f, 0.f};
#pragma unroll
    for (int z = 0; z < 4; ++z) {
        float4 r = *(const float4*)(aspp + (size_t)z * (B * H) + b * H + 4 * t);
        a.x += r.x; a.y += r.y; a.z += r.z; a.w += r.w;
    }
    float4 o = {a.x * inv, a.y * inv, a.z * inv, a.w * inv};
    *(float4*)(aspq + b * H + 4 * t) = o;
}

// ---------------------------------------------------------------------------
// Generic small fp32 GEMM, float4 global loads, 32x32 tiles, z-batch/split-K.
// ---------------------------------------------------------------------------
template <int TAG, int ACT, bool WT, bool HEADSEL, bool KCL>
__global__ void gemm_kernel(const float* __restrict__ A, int lda, int a_bs,
                            const float* __restrict__ W, int ldw, int w_bs,
                            const float* __restrict__ bias,
                            float* __restrict__ C, int ldc, int c_bs,
                            int M, int N, int K, int kclamp) {
    A += (size_t)blockIdx.z * a_bs;
    W += (size_t)blockIdx.z * w_bs;
    C += (size_t)blockIdx.z * c_bs;
    int kcl = KCL ? (kclamp - (int)blockIdx.z * w_bs) : 0;
    int n0 = blockIdx.x * 32, m0 = blockIdx.y * 32;
    if (HEADSEL) A += (n0 / DH) * H;
    __shared__ float As[32][33];
    __shared__ float Ws[32][33];
    int t = threadIdx.x;
    int tx = t & 31, ty = t >> 5;
    int lr = t >> 3, lc = (t & 7) * 4;
    float acc[4] = {0.f, 0.f, 0.f, 0.f};
    for (int k0 = 0; k0 < K; k0 += 32) {
        {
            float4 a = *(const float4*)(A + (size_t)(m0 + lr) * lda + k0 + lc);
            As[lr][lc] = a.x; As[lr][lc + 1] = a.y;
            As[lr][lc + 2] = a.z; As[lr][lc + 3] = a.w;
        }
        if (!WT) {
            int kk = k0 + lc;
            if (KCL) kk = min(kk, kcl);
            float4 w = *(const float4*)(W + (size_t)(n0 + lr) * ldw + kk);
            Ws[lr][lc] = w.x; Ws[lr][lc + 1] = w.y;
            Ws[lr][lc + 2] = w.z; Ws[lr][lc + 3] = w.w;
        } else {
            float4 w = *(const float4*)(W + (size_t)(k0 + lr) * ldw + n0 + lc);
            Ws[lc][lr] = w.x; Ws[lc + 1][lr] = w.y;
            Ws[lc + 2][lr] = w.z; Ws[lc + 3][lr] = w.w;
        }
        __syncthreads();
#pragma unroll
        for (int kk = 0; kk < 32; ++kk) {
            float wv = Ws[tx][kk];
#pragma unroll
            for (int i = 0; i < 4; ++i)
                acc[i] += As[ty + 8 * i][kk] * wv;
        }
        __syncthreads();
    }
    int n = n0 + tx;
    if (n < N) {
        float bb = bias ? bias[n] : 0.f;
#pragma unroll
        for (int i = 0; i < 4; ++i) {
            int m = m0 + ty + 8 * i;
            if (m < M) {
                float x = acc[i] + bb;
                if (ACT == 1) x = 0.5f * x * (1.0f + erff(x * GELU_C));
                C[(size_t)m * ldc + n] = x;
            }
        }
    }
}

// ---------------------------------------------------------------------------
// mergeZ: out[i] = sum_z parts[z][i] + bias[i % ld]   (float4 granular)
// ---------------------------------------------------------------------------
template <int Z>
__global__ void mergeZ_kernel(const float* __restrict__ parts, int pstride,
                              const float* __restrict__ bias, int ld,
                              float* __restrict__ out, int total4) {
    int i = blockIdx.x * 256 + threadIdx.x;
    if (i >= total4) return;
    float4 a = {0.f, 0.f, 0.f, 0.f};
#pragma unroll
    for (int z = 0; z < Z; ++z) {
        float4 p = *(const float4*)(parts + (size_t)z * pstride + 4 * i);
        a.x += p.x; a.y += p.y; a.z += p.z; a.w += p.w;
    }
    int c = (4 * i) % ld;
    float4 bb = *(const float4*)(bias + c);
    float4 o = {a.x + bb.x, a.y + bb.y, a.z + bb.z, a.w + bb.w};
    *(float4*)(out + 4 * i) = o;
}

// ---------------------------------------------------------------------------
// Flash attention pass: one streaming read of lh's text span per (b, slice).
// scores -> online softmax -> weighted accumulate, all fused.
// grid (B, NSL), 768 threads (12 waves). Slice z owns rows s = tlo+z+4j.
// Outputs per (z,b): Op[8][768], (m, l) pairs.
// ---------------------------------------------------------------------------
__global__ __launch_bounds__(768) void flash_kernel(
        const float* __restrict__ lh,
        const float* __restrict__ U,
        const int* __restrict__ sep1,
        float* __restrict__ Op,     // [NSL][B][NH][H]
        float* __restrict__ mlb) {  // [NSL][B][NH][2]
    int b = blockIdx.x, z = blockIdx.y, t = threadIdx.x;
    int wave = t >> 6, lane = t & 63;
    int s1 = sep1[b];
    int tlo = (s1 > 1) ? 1 : 0;
    int thi = (s1 > 1) ? s1 : 1;

    __shared__ float4 Us[NH * 192];      // 24576 B
    __shared__ float lhs[CH][H];         // 36864 B
    __shared__ float sc[CH][NH];
    __shared__ float pr[CH][NH];
    __shared__ float mh[NH], ell[NH], rh[NH];

    const float4* Ub = (const float4*)(U + (size_t)b * NH * H);
    for (int i = t; i < NH * 192; i += 768) Us[i] = Ub[i];
    if (t < NH) { mh[t] = -1e30f; ell[t] = 0.f; }
    float O[NH];
#pragma unroll
    for (int h = 0; h < NH; ++h) O[h] = 0.f;
    __syncthreads();

    for (int s0 = tlo + z; s0 < thi; s0 += NSL * CH) {
        // phase A: wave w computes row s0 + 4w (score + LDS stash)
        int s = s0 + NSL * wave;
        if (s < thi) {
            const float4* row = (const float4*)(lh + ((size_t)b * S + s) * H);
            float4 x0 = row[lane], x1 = row[lane + 64], x2 = row[lane + 128];
            ((float4*)lhs[wave])[lane]       = x0;
            ((float4*)lhs[wave])[lane + 64]  = x1;
            ((float4*)lhs[wave])[lane + 128] = x2;
            float acc[NH];
#pragma unroll
            for (int h = 0; h < NH; ++h) {
                acc[h] = dot4(x0, Us[h * 192 + lane])
                       + dot4(x1, Us[h * 192 + lane + 64])
                       + dot4(x2, Us[h * 192 + lane + 128]);
            }
#pragma unroll
            for (int h = 0; h < NH; ++h) {
                float v = acc[h];
                for (int off = 32; off; off >>= 1) v += __shfl_xor(v, off);
                if (lane == h) sc[wave][h] = v * SCALE;
            }
        } else if (lane < NH) {
            sc[wave][lane] = -1e30f;
        }
        __syncthreads();
        // phase P1: per-head running max + rescale factor
        if (t < NH) {
            float mx = sc[0][t];
#pragma unroll
            for (int r = 1; r < CH; ++r) mx = fmaxf(mx, sc[r][t]);
            float mn = fmaxf(mh[t], mx);
            rh[t] = __expf(mh[t] - mn);
            mh[t] = mn;
        }
        __syncthreads();
        // phase P2: probabilities
        if (t < CH * NH) {
            int r = t >> 3, h = t & 7;
            pr[r][h] = __expf(sc[r][h] - mh[h]);
        }
        __syncthreads();
        // phase P3 + B: l update (threads 0..7) and accumulate (all threads)
        if (t < NH) {
            float ps = 0.f;
#pragma unroll
            for (int r = 0; r < CH; ++r) ps += pr[r][t];
            ell[t] = ell[t] * rh[t] + ps;
        }
        int nvalid = thi - s0;
        nvalid = (nvalid + NSL - 1) / NSL;
        if (nvalid > CH) nvalid = CH;
#pragma unroll
        for (int h = 0; h < NH; ++h) O[h] *= rh[h];
        for (int r = 0; r < nvalid; ++r) {
            float x = lhs[r][t];
#pragma unroll
            for (int h = 0; h < NH; ++h) O[h] += pr[r][h] * x;
        }
        __syncthreads();
    }
    float* Ob = Op + (((size_t)z * B + b) * NH) * H;
#pragma unroll
    for (int h = 0; h < NH; ++h) Ob[h * H + t] = O[h];
    if (t < NH) {
        float* ml = mlb + ((size_t)z * B + b) * NH * 2;
        ml[2 * t]     = mh[t];
        ml[2 * t + 1] = ell[t];
    }
}

// ---------------------------------------------------------------------------
// Flash merge: wsum[b,h,c] = (sum_z O_z e^{m_z-M}) / (sum_z l_z e^{m_z-M})
// grid B, 768 threads.
// ---------------------------------------------------------------------------
__global__ __launch_bounds__(768) void flash_merge_kernel(
        const float* __restrict__ Op,
        const float* __restrict__ mlb,
        float* __restrict__ wsum) {
    int b = blockIdx.x, t = threadIdx.x;
    __shared__ float wz[NSL][NH];
    __shared__ float Linv[NH];
    if (t < NH) {
        float M = -1e30f;
#pragma unroll
        for (int z = 0; z < NSL; ++z)
            M = fmaxf(M, mlb[((size_t)z * B + b) * NH * 2 + 2 * t]);
        float L = 0.f;
#pragma unroll
        for (int z = 0; z < NSL; ++z) {
            const float* ml = mlb + ((size_t)z * B + b) * NH * 2;
            float e = __expf(ml[2 * t] - M);
            wz[z][t] = e;
            L += e * ml[2 * t + 1];
        }
        Linv[t] = 1.0f / L;
    }
    __syncthreads();
#pragma unroll
    for (int h = 0; h < NH; ++h) {
        float a = 0.f;
#pragma unroll
        for (int z = 0; z < NSL; ++z)
            a += Op[(((size_t)z * B + b) * NH + h) * H + t] * wz[z][h];
        wsum[((size_t)b * NH + h) * H + t] = a * Linv[h];
    }
}

// ---------------------------------------------------------------------------
// fuse: fused[b] = [lh[b,0,:], merge(crossp)+out_b, aspq, LN(aro)], zero-pad.
// ---------------------------------------------------------------------------
__global__ void fuse_kernel(const float* __restrict__ lh,
                            const float* __restrict__ crossp,
                            const float* __restrict__ out_b,
                            const float* __restrict__ aspq,
                            const float* __restrict__ aro_f,
                            const float* __restrict__ ln_g,
                            const float* __restrict__ ln_b,
                            float* __restrict__ fused) {
    int b = blockIdx.x, t = threadIdx.x;
    float* fb = fused + (size_t)b * FPAD;
    const float* lhb = lh + (size_t)b * S * H;
    for (int i = t; i < H; i += 256) {
        float cr = out_b[i];
#pragma unroll
        for (int z = 0; z < 6; ++z) cr += crossp[(size_t)z * (B * H) + b * H + i];
        fb[i]         = lhb[i];
        fb[H + i]     = cr;
        fb[2 * H + i] = aspq[b * H + i];
    }
    for (int i = t; i < FPAD - FUSED; i += 256) fb[FUSED + i] = 0.f;
    if (t < 8) {
        const float* af = aro_f + b * 8;
        float mu = 0.f;
#pragma unroll
        for (int j = 0; j < 8; ++j) mu += af[j];
        mu *= 0.125f;
        float var = 0.f;
#pragma unroll
        for (int j = 0; j < 8; ++j) { float d = af[j] - mu; var += d * d; }
        var *= 0.125f;
        fb[3 * H + t] = (af[t] - mu) * rsqrtf(var + 1e-5f) * ln_g[t] + ln_b[t];
    }
}

// ---------------------------------------------------------------------------
// mlp2: reduce hdn1 split-K partials + gelu; hdn2; all 8 head outputs.
// ---------------------------------------------------------------------------
__global__ void mlp2_kernel(const float* __restrict__ hdn1p,
                            const float* __restrict__ fusedb,
                            const float* __restrict__ va_b1,
                            const float* __restrict__ va_w2,
                            const float* __restrict__ va_b2,
                            const float* __restrict__ va_w3,
                            const float* __restrict__ va_b3,
                            const float* __restrict__ pol_w,
                            const float* __restrict__ pol_b,
                            const float* __restrict__ aro_w,
                            const float* __restrict__ aro_b,
                            float* __restrict__ out) {
    int b = blockIdx.x, t = threadIdx.x;
    __shared__ float hs[512];
    __shared__ float h2[128];
    for (int n = t; n < 512; n += 256) {
        float sacc = 0.f;
#pragma unroll
        for (int z = 0; z < KSPLIT; ++z)
            sacc += hdn1p[(size_t)z * (B * 512) + b * 512 + n];
        sacc += va_b1[n];
        hs[n] = 0.5f * sacc * (1.0f + erff(sacc * GELU_C));
    }
    __syncthreads();
    int wave = t >> 6, lane = t & 63;
    for (int i = 0; i < 32; ++i) {
        int n = wave * 32 + i;
        float a = 0.f;
#pragma unroll
        for (int j = 0; j < 8; ++j) {
            int k = lane + 64 * j;
            a += hs[k] * va_w2[(size_t)n * 512 + k];
        }
        for (int off = 32; off; off >>= 1) a += __shfl_xor(a, off);
        if (lane == 0) {
            float x = a + va_b2[n];
            h2[n] = 0.5f * x * (1.0f + erff(x * GELU_C));
        }
    }
    __syncthreads();
    const float* fb = fusedb + (size_t)b * FPAD;
    for (int oi = 0; oi < 2; ++oi) {
        int o = wave * 2 + oi;
        float acc = 0.f, bia;
        float* dst;
        if (o < 2) {
            for (int k = lane; k < 128; k += 64) acc += h2[k] * va_w3[o * 128 + k];
            bia = va_b3[o]; dst = out + b * 2 + o;
        } else if (o < 5) {
            int r = o - 2;
            for (int k = lane; k < FUSED; k += 64) acc += fb[k] * pol_w[(size_t)r * FUSED + k];
            bia = pol_b[r]; dst = out + 256 + b * 3 + r;
        } else {
            int r = o - 5;
            for (int k = lane; k < FUSED; k += 64) acc += fb[k] * aro_w[(size_t)r * FUSED + k];
            bia = aro_b[r]; dst = out + 640 + b * 3 + r;
        }
        for (int off = 32; off; off >>= 1) acc += __shfl_xor(acc, off);
        if (lane == 0) *dst = acc + bia;
    }
}

// ---------------------------------------------------------------------------
extern "C" void kernel_launch(void* const* d_in, const int* in_sizes, int n_in,
                              void* d_out, int out_size, void* d_ws, size_t ws_size,
                              hipStream_t stream) {
    const float* lh    = (const float*)d_in[0];
    const float* aro_f = (const float*)d_in[1];
    const int*   sep1  = (const int*)d_in[2];
    const int*   sep2  = (const int*)d_in[3];
    const float* in_w  = (const float*)d_in[4];
    const float* in_b  = (const float*)d_in[5];
    const float* out_w = (const float*)d_in[6];
    const float* out_b = (const float*)d_in[7];
    const float* ln_g  = (const float*)d_in[8];
    const float* ln_b  = (const float*)d_in[9];
    const float* va_w1 = (const float*)d_in[10];
    const float* va_b1 = (const float*)d_in[11];
    const float* va_w2 = (const float*)d_in[12];
    const float* va_b2 = (const float*)d_in[13];
    const float* va_w3 = (const float*)d_in[14];
    const float* va_b3 = (const float*)d_in[15];
    const float* pol_w = (const float*)d_in[16];
    const float* pol_b = (const float*)d_in[17];
    const float* aro_w = (const float*)d_in[18];
    const float* aro_b = (const float*)d_in[19];
    float* out = (float*)d_out;

    float* ws = (float*)d_ws;
    float* aspp   = ws;                          // 4*B*H
    float* aspq   = aspp + 4 * B * H;            // B*H
    float* qp     = aspq + B * H;                // 6*B*H
    float* qbuf   = qp + 6 * B * H;              // B*H
    float* Ubuf   = qbuf + B * H;                // B*NH*H
    float* Opb    = Ubuf + B * NH * H;           // NSL*B*NH*H
    float* mlbuf  = Opb + NSL * B * NH * H;      // NSL*B*NH*2
    float* wsumb  = mlbuf + NSL * B * NH * 2;    // B*NH*H
    float* ctxp   = wsumb + B * NH * H;          // 6*B*H
    float* ctx    = ctxp + 6 * B * H;            // B*H
    float* crossp = ctx + B * H;                 // 6*B*H
    float* fusedb = crossp + 6 * B * H;          // B*FPAD
    float* hdn1p  = fusedb + B * FPAD;           // 19*B*512

    const float* wq = in_w;
    const float* wk = in_w + H * H;
    const float* wv = in_w + 2 * H * H;
    const float* bq = in_b;
    const float* bv = in_b + 2 * H;

    // 1) asp_query (partials + merge)
    aspq_part_kernel<<<dim3(B, 4), 192, 0, stream>>>(lh, sep1, sep2, aspp);
    aspq_merge_kernel<<<B, 192, 0, stream>>>(aspp, sep1, sep2, aspq);
    // 2) q = aspq @ wq.T (+bq via merge): split-K 6x128
    gemm_kernel<0, 0, false, false, false><<<dim3(24, 4, 6), 256, 0, stream>>>(
        aspq, H, KCHUNK, wq, H, KCHUNK, nullptr, qp, H, B * H, B, H, KCHUNK, 0);
    mergeZ_kernel<6><<<(B * H / 4 + 255) / 256, 256, 0, stream>>>(
        qp, B * H, bq, H, qbuf, B * H / 4);
    // 3) U[b,h,:] = q_h @ wk_h   (z = head, K=96)
    gemm_kernel<1, 0, true, false, false><<<dim3(24, 4, NH), 256, 0, stream>>>(
        qbuf, H, DH, wk, H, DH * H, nullptr, Ubuf, NH * H, H, B, H, DH, 0);
    // 4) flash: scores+softmax+weighted-sum in one pass over lh text span
    flash_kernel<<<dim3(B, NSL), 768, 0, stream>>>(lh, Ubuf, sep1, Opb, mlbuf);
    flash_merge_kernel<<<B, 768, 0, stream>>>(Opb, mlbuf, wsumb);
    // 5) ctx = wv_h @ wsum_h (+bv via merge): split-K 6x128, head-block-diag A
    gemm_kernel<2, 0, false, true, false><<<dim3(24, 4, 6), 256, 0, stream>>>(
        wsumb, NH * H, KCHUNK, wv, H, KCHUNK, nullptr, ctxp, H, B * H, B, H, KCHUNK, 0);
    mergeZ_kernel<6><<<(B * H / 4 + 255) / 256, 256, 0, stream>>>(
        ctxp, B * H, bv, H, ctx, B * H / 4);
    // 6) cross partials = ctx @ out_w.T : split-K 6x128 (merged in fuse)
    gemm_kernel<3, 0, false, false, false><<<dim3(24, 4, 6), 256, 0, stream>>>(
        ctx, H, KCHUNK, out_w, H, KCHUNK, nullptr, crossp, H, B * H, B, H, KCHUNK, 0);
    // 7) fused assembly (+cross merge, +LN, +pad)
    fuse_kernel<<<B, 256, 0, stream>>>(lh, crossp, out_b, aspq, aro_f,
                                       ln_g, ln_b, fusedb);
    // 8) hdn1 split-K partials (19 x 128)
    gemm_kernel<4, 0, false, false, true><<<dim3(16, 4, KSPLIT), 256, 0, stream>>>(
        fusedb, FPAD, KCHUNK, va_w1, FUSED, KCHUNK, nullptr,
        hdn1p, 512, B * 512, B, 512, KCHUNK, FUSED - 4);
    // 9) mlp2: reduce+gelu + hdn2 + heads
    mlp2_kernel<<<B, 256, 0, stream>>>(hdn1p, fusedb, va_b1, va_w2, va_b2,
                                       va_w3, va_b3, pol_w, pol_b,
                                       aro_w, aro_b, out);
}